// Round 3
// baseline (158.049 us; speedup 1.0000x reference)
//
#include <hip/hip_runtime.h>

#define B_ 8
#define A_ 98304
#define C_ 80
#define M_ 32
#define BLK 256

// phase-2 term: u = p^2 * log2(1-p); negative-anchor loss = 0.75*p^2*(-ln(1-p)) = u * NEGC
#define NEGC (-0.75f * 0.69314718055994531f)

#define P2_BLOCKS 256                        // blocks per image in phase 2
#define F4_PER_IMG (A_ * C_ / 4)             // 1,966,080 float4 per image
#define F4_PER_BLK (F4_PER_IMG / P2_BLOCKS)  // 7,680
#define P2_ITERS (F4_PER_BLK / BLK)          // 30 per thread

// negative-form core term (IDENTICAL in phase-1 correction and phase-2 sweep)
__device__ __forceinline__ float neg_u(float praw) {
    const float p = fminf(fmaxf(praw, 1e-4f), 1.0f - 1e-4f);
    return p * p * __log2f(1.0f - p);
}

__device__ __forceinline__ float smooth_l1(float t, float r) {
    float d = fabsf(t - r);
    return (d <= (1.0f / 9.0f)) ? (0.5f * 9.0f * d * d) : (d - 0.5f / 9.0f);
}

// ---------------- phase 1: per-anchor assignment ----------------
__global__ __launch_bounds__(BLK) void focal_phase1(
    const float* __restrict__ cls,      // [B,A,C]
    const float* __restrict__ regr,     // [B,A,4]
    const float* __restrict__ anchors,  // [A,4]
    const float* __restrict__ ann,      // [B,M,5]
    const float* __restrict__ neg_thr_p,
    const float* __restrict__ pos_thr_p,
    float* __restrict__ acc,            // [B,3] : cls_sum, reg_sum, num_pos
    float* __restrict__ w)              // [B,A] per-anchor phase-2 weight
{
    __shared__ float s_x0[M_], s_y0[M_], s_x1[M_], s_y1[M_], s_ab[M_], s_cls[M_];
    __shared__ float s_red[(BLK / 64) * 3];

    const int tid = threadIdx.x;
    const int blocksPerImg = A_ / BLK;  // 384
    const int b  = blockIdx.x / blocksPerImg;
    const int a0 = (blockIdx.x % blocksPerImg) * BLK;

    if (tid < M_) {
        const float* am = ann + ((size_t)b * M_ + tid) * 5;
        const float x0 = am[0], y0 = am[1], x1 = am[2], y1 = am[3], cl = am[4];
        s_x0[tid] = x0; s_y0[tid] = y0; s_x1[tid] = x1; s_y1[tid] = y1;
        s_ab[tid] = (x1 - x0) * (y1 - y0);
        s_cls[tid] = cl;
    }
    __syncthreads();

    const float neg_thr = neg_thr_p[0];
    const float pos_thr = pos_thr_p[0];

    // IoU argmax via cross-multiplication (no divisions)
    const int a = a0 + tid;
    const float4 an = reinterpret_cast<const float4*>(anchors)[a];
    const float aw = an.z - an.x;
    const float ah = an.w - an.y;
    const float areaA = aw * ah;

    float ib = -1.0f, ub = 1.0f;   // best inter / best union (iou = ib/ub)
    int   arg = 0;
#pragma unroll
    for (int m = 0; m < M_; ++m) {
        const float iw = fmaxf(fminf(an.z, s_x1[m]) - fmaxf(an.x, s_x0[m]), 0.0f);
        const float ih = fmaxf(fminf(an.w, s_y1[m]) - fmaxf(an.y, s_y0[m]), 0.0f);
        float inter = iw * ih;
        const float ua = fmaxf(areaA + s_ab[m] - inter, 1e-8f);
        if (s_cls[m] == -1.0f) inter = -1.0f;          // invalid annotation -> iou -1
        if (inter * ub > ib * ua) { ib = inter; ub = ua; arg = m; }
    }
    const bool pos = (ib >= pos_thr * ub);
    const bool neg = (ib <  neg_thr * ub);

    float reg_partial = 0.0f;
    float pos_count   = 0.0f;
    float cls_corr    = 0.0f;

    if (pos) {
        pos_count = 1.0f;
        const float gx0 = s_x0[arg], gy0 = s_y0[arg];
        const float gx1 = s_x1[arg], gy1 = s_y1[arg];
        const int   kcls = (int)s_cls[arg];

        float gw = gx1 - gx0;
        float gh = gy1 - gy0;
        const float gcx = gx0 + 0.5f * gw;
        const float gcy = gy0 + 0.5f * gh;
        gw = fmaxf(gw, 1.0f);
        gh = fmaxf(gh, 1.0f);
        const float acx = an.x + 0.5f * aw;
        const float acy = an.y + 0.5f * ah;
        const float t0 = ((gcx - acx) / aw) * 10.0f;
        const float t1 = ((gcy - acy) / ah) * 10.0f;
        const float t2 = logf(gw / aw) * 5.0f;
        const float t3 = logf(gh / ah) * 5.0f;
        const float4 r = reinterpret_cast<const float4*>(regr)[(size_t)b * A_ + a];
        reg_partial = smooth_l1(t0, r.x) + smooth_l1(t1, r.y) +
                      smooth_l1(t2, r.z) + smooth_l1(t3, r.w);

        // classification correction for the single assigned class:
        // phase 2 will add the neg-form for it; replace with pos-form here.
        const float praw = cls[((size_t)b * A_ + a) * C_ + kcls];
        const float p  = fminf(fmaxf(praw, 1e-4f), 1.0f - 1e-4f);
        const float om = 1.0f - p;
        const float negv = neg_u(praw) * NEGC;
        const float posv = 0.25f * om * om * (-__logf(p));
        cls_corr = posv - negv;
    }
    w[(size_t)b * A_ + a] = (pos || neg) ? NEGC : 0.0f;

    // block reduction: 3 values
#pragma unroll
    for (int off = 32; off > 0; off >>= 1) {
        cls_corr    += __shfl_down(cls_corr,    off);
        reg_partial += __shfl_down(reg_partial, off);
        pos_count   += __shfl_down(pos_count,   off);
    }
    const int wave = tid >> 6;
    if ((tid & 63) == 0) {
        s_red[wave * 3 + 0] = cls_corr;
        s_red[wave * 3 + 1] = reg_partial;
        s_red[wave * 3 + 2] = pos_count;
    }
    __syncthreads();
    if (tid == 0) {
        float c = 0.0f, r = 0.0f, n = 0.0f;
#pragma unroll
        for (int wv = 0; wv < BLK / 64; ++wv) {
            c += s_red[wv * 3 + 0];
            r += s_red[wv * 3 + 1];
            n += s_red[wv * 3 + 2];
        }
        if (c != 0.0f) atomicAdd(&acc[b * 3 + 0], c);
        if (r != 0.0f) atomicAdd(&acc[b * 3 + 1], r);
        if (n != 0.0f) atomicAdd(&acc[b * 3 + 2], n);
    }
}

// ---------------- phase 2: pure streaming sweep ----------------
__global__ __launch_bounds__(BLK) void focal_phase2(
    const float4* __restrict__ cls4,    // [B * A * C / 4]
    const float* __restrict__ w,        // [B,A]
    float* __restrict__ acc)            // [B,3]
{
    const int tid = threadIdx.x;
    const int b   = blockIdx.x / P2_BLOCKS;
    const int blk = blockIdx.x % P2_BLOCKS;
    const int lbase = blk * F4_PER_BLK;
    const float4* img = cls4 + (size_t)b * F4_PER_IMG;
    const float*  wb  = w + (size_t)b * A_;

    float s = 0.0f;
#pragma unroll 6
    for (int it = 0; it < P2_ITERS; ++it) {          // 30 iters
        const int li = lbase + it * BLK + tid;       // f4 idx within image, coalesced
        const float4 v = img[li];
        const float cw = wb[(unsigned)li / 20u];     // 20 float4 per anchor row
        const float u = (neg_u(v.x) + neg_u(v.y)) + (neg_u(v.z) + neg_u(v.w));
        s = fmaf(u, cw, s);
    }

#pragma unroll
    for (int off = 32; off > 0; off >>= 1) s += __shfl_down(s, off);
    __shared__ float red[BLK / 64];
    if ((tid & 63) == 0) red[tid >> 6] = s;
    __syncthreads();
    if (tid == 0) {
        float t = 0.0f;
#pragma unroll
        for (int i2 = 0; i2 < BLK / 64; ++i2) t += red[i2];
        atomicAdd(&acc[b * 3 + 0], t);
    }
}

__global__ void focal_finalize(const float* __restrict__ acc, float* __restrict__ out) {
    const int t = threadIdx.x;
    float cls_l = 0.0f, reg_l = 0.0f;
    if (t < B_) {
        const float np = acc[t * 3 + 2];
        cls_l = acc[t * 3 + 0] / fmaxf(np, 1.0f);
        reg_l = acc[t * 3 + 1] / fmaxf(np * 4.0f, 1.0f);
    }
#pragma unroll
    for (int off = 32; off > 0; off >>= 1) {
        cls_l += __shfl_down(cls_l, off);
        reg_l += __shfl_down(reg_l, off);
    }
    if (t == 0) {
        out[0] = cls_l / (float)B_;
        out[1] = reg_l / (float)B_;
    }
}

extern "C" void kernel_launch(void* const* d_in, const int* in_sizes, int n_in,
                              void* d_out, int out_size, void* d_ws, size_t ws_size,
                              hipStream_t stream) {
    const float* cls     = (const float*)d_in[0];
    const float* regr    = (const float*)d_in[1];
    const float* anchors = (const float*)d_in[2];
    const float* ann     = (const float*)d_in[3];
    const float* negt    = (const float*)d_in[4];
    const float* post    = (const float*)d_in[5];

    float* acc = (float*)d_ws;                 // [B,3]
    float* w   = (float*)d_ws + 64;            // [B,A], 256B-offset from acc

    hipMemsetAsync(acc, 0, B_ * 3 * sizeof(float), stream);
    focal_phase1<<<B_ * (A_ / BLK), BLK, 0, stream>>>(cls, regr, anchors, ann,
                                                      negt, post, acc, w);
    focal_phase2<<<B_ * P2_BLOCKS, BLK, 0, stream>>>(
        reinterpret_cast<const float4*>(cls), w, acc);
    focal_finalize<<<1, 64, 0, stream>>>(acc, (float*)d_out);
}

// Round 4
// 130.072 us; speedup vs baseline: 1.2151x; 1.2151x over previous
//
#include <hip/hip_runtime.h>

#define B_ 8
#define A_ 98304
#define C_ 80
#define M_ 32
#define BLK 320      // 5 waves; 320 % 20 == 0 makes anchor index loop-invariant
#define ANCH 256     // anchors per block
#define ITERS 16     // (ANCH*C_/4) / BLK = 5120/320
#define NWAVE (BLK / 64)

// phase-2 term: u = p^2 * log2(1-p); negative-anchor loss = 0.75*p^2*(-ln(1-p)) = u * NEGC
#define NEGC (-0.75f * 0.69314718055994531f)

// negative-form core (IDENTICAL in phase-1 correction and phase-2 sweep).
// Lower clamp dropped: for p<1e-4 both ref and this are < 1.5e-12 in |loss|.
__device__ __forceinline__ float neg_u(float praw) {
    const float p = fminf(praw, 1.0f - 1e-4f);
    return p * p * __log2f(1.0f - p);
}

__device__ __forceinline__ float smooth_l1(float t, float r) {
    float d = fabsf(t - r);
    return (d <= (1.0f / 9.0f)) ? (0.5f * 9.0f * d * d) : (d - 0.5f / 9.0f);
}

__global__ __launch_bounds__(BLK) void focal_main(
    const float* __restrict__ cls,      // [B,A,C]
    const float* __restrict__ regr,     // [B,A,4]
    const float* __restrict__ anchors,  // [A,4]
    const float* __restrict__ ann,      // [B,M,5]
    const float* __restrict__ neg_thr_p,
    const float* __restrict__ pos_thr_p,
    float* __restrict__ acc)            // [B,3] : cls_sum, reg_sum, num_pos
{
    __shared__ float s_x0[M_], s_y0[M_], s_x1[M_], s_y1[M_], s_ab[M_], s_cls[M_];
    __shared__ float s_w[ANCH];
    __shared__ float s_red[NWAVE * 3];

    const int tid = threadIdx.x;
    const int blocksPerImg = A_ / ANCH;  // 384
    const int b  = blockIdx.x / blocksPerImg;
    const int a0 = (blockIdx.x % blocksPerImg) * ANCH;

    if (tid < M_) {
        const float* am = ann + ((size_t)b * M_ + tid) * 5;
        const float x0 = am[0], y0 = am[1], x1 = am[2], y1 = am[3], cl = am[4];
        s_x0[tid] = x0; s_y0[tid] = y0; s_x1[tid] = x1; s_y1[tid] = y1;
        s_ab[tid] = (x1 - x0) * (y1 - y0);
        s_cls[tid] = cl;
    }
    __syncthreads();

    const float neg_thr = neg_thr_p[0];
    const float pos_thr = pos_thr_p[0];

    // ---- phase 1 (threads 0..ANCH-1): IoU argmax via cross-multiplication ----
    float reg_partial = 0.0f;
    float pos_count   = 0.0f;
    float cls_corr    = 0.0f;

    if (tid < ANCH) {
        const int a = a0 + tid;
        const float4 an = reinterpret_cast<const float4*>(anchors)[a];
        const float aw = an.z - an.x;
        const float ah = an.w - an.y;
        const float areaA = aw * ah;

        float ib = -1.0f, ub = 1.0f;   // best inter / best union (iou = ib/ub)
        int   arg = 0;
#pragma unroll
        for (int m = 0; m < M_; ++m) {
            const float iw = fmaxf(fminf(an.z, s_x1[m]) - fmaxf(an.x, s_x0[m]), 0.0f);
            const float ih = fmaxf(fminf(an.w, s_y1[m]) - fmaxf(an.y, s_y0[m]), 0.0f);
            float inter = iw * ih;
            const float ua = fmaxf(areaA + s_ab[m] - inter, 1e-8f);
            if (s_cls[m] == -1.0f) inter = -1.0f;      // invalid annotation -> iou -1
            if (inter * ub > ib * ua) { ib = inter; ub = ua; arg = m; }
        }
        const bool pos = (ib >= pos_thr * ub);
        const bool neg = (ib <  neg_thr * ub);

        if (pos) {
            pos_count = 1.0f;
            const float gx0 = s_x0[arg], gy0 = s_y0[arg];
            const float gx1 = s_x1[arg], gy1 = s_y1[arg];
            const int   kcls = (int)s_cls[arg];

            float gw = gx1 - gx0;
            float gh = gy1 - gy0;
            const float gcx = gx0 + 0.5f * gw;
            const float gcy = gy0 + 0.5f * gh;
            gw = fmaxf(gw, 1.0f);
            gh = fmaxf(gh, 1.0f);
            const float acx = an.x + 0.5f * aw;
            const float acy = an.y + 0.5f * ah;
            const float t0 = ((gcx - acx) / aw) * 10.0f;
            const float t1 = ((gcy - acy) / ah) * 10.0f;
            const float t2 = logf(gw / aw) * 5.0f;
            const float t3 = logf(gh / ah) * 5.0f;
            const float4 r = reinterpret_cast<const float4*>(regr)[(size_t)b * A_ + a];
            reg_partial = smooth_l1(t0, r.x) + smooth_l1(t1, r.y) +
                          smooth_l1(t2, r.z) + smooth_l1(t3, r.w);

            // replace phase-2's neg-form on the assigned class with the pos-form
            const float praw = cls[((size_t)b * A_ + a) * C_ + kcls];
            const float p  = fminf(fmaxf(praw, 1e-4f), 1.0f - 1e-4f);
            const float om = 1.0f - p;
            const float negv = neg_u(praw) * NEGC;
            const float posv = 0.25f * om * om * (-__logf(p));
            cls_corr = posv - negv;
        }
        s_w[tid] = (pos || neg) ? NEGC : 0.0f;         // ignored anchors weight 0
    }
    __syncthreads();

    // ---- phase 2: coalesced float4 sweep, loop-invariant anchor row ----
    const float4* tile = reinterpret_cast<const float4*>(
        cls + ((size_t)b * A_ + a0) * C_);
    const int arow = tid / 20;                         // hoisted: 320 % 20 == 0
    float s0 = 0.0f, s1 = 0.0f;
#pragma unroll 4
    for (int it = 0; it < ITERS; ++it) {               // 16 iters
        const float4 v = tile[it * BLK + tid];
        const float cw = s_w[it * 16 + arow];
        const float u01 = neg_u(v.x) + neg_u(v.y);
        const float u23 = neg_u(v.z) + neg_u(v.w);
        s0 = fmaf(u01, cw, s0);
        s1 = fmaf(u23, cw, s1);
    }
    float cls_partial = cls_corr + s0 + s1;

    // ---- block reduction: 3 values over 5 waves ----
#pragma unroll
    for (int off = 32; off > 0; off >>= 1) {
        cls_partial += __shfl_down(cls_partial, off);
        reg_partial += __shfl_down(reg_partial, off);
        pos_count   += __shfl_down(pos_count,   off);
    }
    const int wave = tid >> 6;
    if ((tid & 63) == 0) {
        s_red[wave * 3 + 0] = cls_partial;
        s_red[wave * 3 + 1] = reg_partial;
        s_red[wave * 3 + 2] = pos_count;
    }
    __syncthreads();
    if (tid == 0) {
        float c = 0.0f, r = 0.0f, n = 0.0f;
#pragma unroll
        for (int wv = 0; wv < NWAVE; ++wv) {
            c += s_red[wv * 3 + 0];
            r += s_red[wv * 3 + 1];
            n += s_red[wv * 3 + 2];
        }
        atomicAdd(&acc[b * 3 + 0], c);
        atomicAdd(&acc[b * 3 + 1], r);
        atomicAdd(&acc[b * 3 + 2], n);
    }
}

__global__ void focal_finalize(const float* __restrict__ acc, float* __restrict__ out) {
    const int t = threadIdx.x;
    float cls_l = 0.0f, reg_l = 0.0f;
    if (t < B_) {
        const float np = acc[t * 3 + 2];
        cls_l = acc[t * 3 + 0] / fmaxf(np, 1.0f);
        reg_l = acc[t * 3 + 1] / fmaxf(np * 4.0f, 1.0f);
    }
#pragma unroll
    for (int off = 32; off > 0; off >>= 1) {
        cls_l += __shfl_down(cls_l, off);
        reg_l += __shfl_down(reg_l, off);
    }
    if (t == 0) {
        out[0] = cls_l / (float)B_;
        out[1] = reg_l / (float)B_;
    }
}

extern "C" void kernel_launch(void* const* d_in, const int* in_sizes, int n_in,
                              void* d_out, int out_size, void* d_ws, size_t ws_size,
                              hipStream_t stream) {
    const float* cls     = (const float*)d_in[0];
    const float* regr    = (const float*)d_in[1];
    const float* anchors = (const float*)d_in[2];
    const float* ann     = (const float*)d_in[3];
    const float* negt    = (const float*)d_in[4];
    const float* post    = (const float*)d_in[5];
    float* acc = (float*)d_ws;

    hipMemsetAsync(acc, 0, B_ * 3 * sizeof(float), stream);
    focal_main<<<B_ * (A_ / ANCH), BLK, 0, stream>>>(cls, regr, anchors, ann,
                                                     negt, post, acc);
    focal_finalize<<<1, 64, 0, stream>>>(acc, (float*)d_out);
}

// Round 5
// 116.488 us; speedup vs baseline: 1.3568x; 1.1166x over previous
//
#include <hip/hip_runtime.h>

#define B_ 8
#define A_ 98304
#define C_ 80
#define M_ 32
#define BLK 256
#define ITERS 20     // (BLK anchors * C_ / 4 floats) / BLK threads
#define NPF 10       // prefetch depth: float4 loads in flight per thread
#define NWAVE (BLK / 64)

// phase-2 term: u = p^2 * log2(1-p); negative-anchor loss = 0.75*p^2*(-ln(1-p)) = u * NEGC
#define NEGC (-0.75f * 0.69314718055994531f)

// negative-form core (IDENTICAL in phase-1 correction and phase-2 sweep).
// Lower clamp dropped: for p<1e-4 the term is < 1.5e-12 (validated R4, absmax 0).
__device__ __forceinline__ float neg_u(float praw) {
    const float p = fminf(praw, 1.0f - 1e-4f);
    return p * p * __log2f(1.0f - p);
}

__device__ __forceinline__ float smooth_l1(float t, float r) {
    float d = fabsf(t - r);
    return (d <= (1.0f / 9.0f)) ? (0.5f * 9.0f * d * d) : (d - 0.5f / 9.0f);
}

__global__ __launch_bounds__(BLK, 4) void focal_main(
    const float* __restrict__ cls,      // [B,A,C]
    const float* __restrict__ regr,     // [B,A,4]
    const float* __restrict__ anchors,  // [A,4]
    const float* __restrict__ ann,      // [B,M,5]
    const float* __restrict__ neg_thr_p,
    const float* __restrict__ pos_thr_p,
    float* __restrict__ acc)            // [B,3] : cls_sum, reg_sum, num_pos
{
    __shared__ float s_x0[M_], s_y0[M_], s_x1[M_], s_y1[M_], s_ab[M_], s_cls[M_];
    __shared__ float s_w[BLK];
    __shared__ float s_red[NWAVE * 3];

    const int tid = threadIdx.x;
    const int blocksPerImg = A_ / BLK;  // 384
    const int b  = blockIdx.x / blocksPerImg;
    const int a0 = (blockIdx.x % blocksPerImg) * BLK;

    if (tid < M_) {
        const float* am = ann + ((size_t)b * M_ + tid) * 5;
        const float x0 = am[0], y0 = am[1], x1 = am[2], y1 = am[3], cl = am[4];
        s_x0[tid] = x0; s_y0[tid] = y0; s_x1[tid] = x1; s_y1[tid] = y1;
        s_ab[tid] = (x1 - x0) * (y1 - y0);
        s_cls[tid] = cl;
    }
    __syncthreads();

    const float neg_thr = neg_thr_p[0];
    const float pos_thr = pos_thr_p[0];

    // ---- phase 1: IoU argmax via cross-multiplication (no divisions) ----
    const int a = a0 + tid;
    const float4 an = reinterpret_cast<const float4*>(anchors)[a];
    const float aw = an.z - an.x;
    const float ah = an.w - an.y;
    const float areaA = aw * ah;

    float ib = -1.0f, ub = 1.0f;   // best inter / best union (iou = ib/ub)
    int   arg = 0;
#pragma unroll
    for (int m = 0; m < M_; ++m) {
        const float iw = fmaxf(fminf(an.z, s_x1[m]) - fmaxf(an.x, s_x0[m]), 0.0f);
        const float ih = fmaxf(fminf(an.w, s_y1[m]) - fmaxf(an.y, s_y0[m]), 0.0f);
        float inter = iw * ih;
        const float ua = fmaxf(areaA + s_ab[m] - inter, 1e-8f);
        if (s_cls[m] == -1.0f) inter = -1.0f;          // invalid annotation -> iou -1
        if (inter * ub > ib * ua) { ib = inter; ub = ua; arg = m; }
    }
    const bool pos = (ib >= pos_thr * ub);
    const bool neg = (ib <  neg_thr * ub);

    float reg_partial = 0.0f;
    float pos_count   = 0.0f;
    float cls_corr    = 0.0f;

    if (pos) {
        pos_count = 1.0f;
        const float gx0 = s_x0[arg], gy0 = s_y0[arg];
        const float gx1 = s_x1[arg], gy1 = s_y1[arg];
        const int   kcls = (int)s_cls[arg];

        float gw = gx1 - gx0;
        float gh = gy1 - gy0;
        const float gcx = gx0 + 0.5f * gw;
        const float gcy = gy0 + 0.5f * gh;
        gw = fmaxf(gw, 1.0f);
        gh = fmaxf(gh, 1.0f);
        const float acx = an.x + 0.5f * aw;
        const float acy = an.y + 0.5f * ah;
        const float t0 = ((gcx - acx) / aw) * 10.0f;
        const float t1 = ((gcy - acy) / ah) * 10.0f;
        const float t2 = logf(gw / aw) * 5.0f;
        const float t3 = logf(gh / ah) * 5.0f;
        const float4 r = reinterpret_cast<const float4*>(regr)[(size_t)b * A_ + a];
        reg_partial = smooth_l1(t0, r.x) + smooth_l1(t1, r.y) +
                      smooth_l1(t2, r.z) + smooth_l1(t3, r.w);

        // replace phase-2's neg-form on the assigned class with the pos-form
        const float praw = cls[((size_t)b * A_ + a) * C_ + kcls];
        const float p  = fminf(fmaxf(praw, 1e-4f), 1.0f - 1e-4f);
        const float om = 1.0f - p;
        const float negv = neg_u(praw) * NEGC;
        const float posv = 0.25f * om * om * (-__logf(p));
        cls_corr = posv - negv;
    }
    s_w[tid] = (pos || neg) ? NEGC : 0.0f;             // ignored anchors weight 0
    __syncthreads();

    // ---- phase 2: 10-deep software-pipelined coalesced float4 sweep ----
    const float4* tile = reinterpret_cast<const float4*>(
        cls + ((size_t)b * A_ + a0) * C_);

    float4 buf[NPF];
#pragma unroll
    for (int i = 0; i < NPF; ++i) buf[i] = tile[i * BLK + tid];

    float s0 = 0.0f, s1 = 0.0f;
#pragma unroll
    for (int i = 0; i < ITERS; ++i) {                  // fully unrolled: static idx
        const float4 v = buf[i % NPF];
        if (i + NPF < ITERS)                           // refill slot immediately
            buf[i % NPF] = tile[(i + NPF) * BLK + tid];
        const int arow = (i * BLK + tid) / 20;         // 20 float4 per anchor row
        const float cw = s_w[arow];
        s0 = fmaf(neg_u(v.x) + neg_u(v.y), cw, s0);
        s1 = fmaf(neg_u(v.z) + neg_u(v.w), cw, s1);
    }
    float cls_partial = cls_corr + s0 + s1;

    // ---- block reduction: 3 values ----
#pragma unroll
    for (int off = 32; off > 0; off >>= 1) {
        cls_partial += __shfl_down(cls_partial, off);
        reg_partial += __shfl_down(reg_partial, off);
        pos_count   += __shfl_down(pos_count,   off);
    }
    const int wave = tid >> 6;
    if ((tid & 63) == 0) {
        s_red[wave * 3 + 0] = cls_partial;
        s_red[wave * 3 + 1] = reg_partial;
        s_red[wave * 3 + 2] = pos_count;
    }
    __syncthreads();
    if (tid == 0) {
        float c = 0.0f, r = 0.0f, n = 0.0f;
#pragma unroll
        for (int wv = 0; wv < NWAVE; ++wv) {
            c += s_red[wv * 3 + 0];
            r += s_red[wv * 3 + 1];
            n += s_red[wv * 3 + 2];
        }
        atomicAdd(&acc[b * 3 + 0], c);
        atomicAdd(&acc[b * 3 + 1], r);
        atomicAdd(&acc[b * 3 + 2], n);
    }
}

__global__ void focal_finalize(const float* __restrict__ acc, float* __restrict__ out) {
    const int t = threadIdx.x;
    float cls_l = 0.0f, reg_l = 0.0f;
    if (t < B_) {
        const float np = acc[t * 3 + 2];
        cls_l = acc[t * 3 + 0] / fmaxf(np, 1.0f);
        reg_l = acc[t * 3 + 1] / fmaxf(np * 4.0f, 1.0f);
    }
#pragma unroll
    for (int off = 32; off > 0; off >>= 1) {
        cls_l += __shfl_down(cls_l, off);
        reg_l += __shfl_down(reg_l, off);
    }
    if (t == 0) {
        out[0] = cls_l / (float)B_;
        out[1] = reg_l / (float)B_;
    }
}

extern "C" void kernel_launch(void* const* d_in, const int* in_sizes, int n_in,
                              void* d_out, int out_size, void* d_ws, size_t ws_size,
                              hipStream_t stream) {
    const float* cls     = (const float*)d_in[0];
    const float* regr    = (const float*)d_in[1];
    const float* anchors = (const float*)d_in[2];
    const float* ann     = (const float*)d_in[3];
    const float* negt    = (const float*)d_in[4];
    const float* post    = (const float*)d_in[5];
    float* acc = (float*)d_ws;

    hipMemsetAsync(acc, 0, B_ * 3 * sizeof(float), stream);
    focal_main<<<B_ * (A_ / BLK), BLK, 0, stream>>>(cls, regr, anchors, ann,
                                                    negt, post, acc);
    focal_finalize<<<1, 64, 0, stream>>>(acc, (float*)d_out);
}